// Round 9
// baseline (1278.338 us; speedup 1.0000x reference)
//
#include <hip/hip_runtime.h>
#include <hip/hip_cooperative_groups.h>

namespace cg = cooperative_groups;

#define NN 100000
#define NE 640000
#define IND 128
#define HD 256
#define NC 40
#define MT 64      // nodes per block in MLP
#define HPAD 264   // h_s row stride (bf16 elems)
#define LPAD 52    // l_s row stride (f32)

typedef unsigned short u16;
typedef unsigned int u32;
typedef __attribute__((ext_vector_type(8))) short bf16x8;
typedef __attribute__((ext_vector_type(4))) float f32x4;

__device__ __forceinline__ float bf2f(u16 u) {
    union { u32 i; float f; } c; c.i = ((u32)u) << 16; return c.f;
}
__device__ __forceinline__ u16 f2bf(float f) {
    union { float f; u32 i; } c; c.f = f;
    u32 i = c.i;
    return (u16)((i + 0x7FFFu + ((i >> 16) & 1u)) >> 16); // RNE
}

struct GArgs {
    const int* src; const int* dst; const float* feats;
    const float* W1; const float* W2;
    int* deg; int* rowptr; int* cursor; float* norm;
    int* bsum; int* boff; int2* cv;
    u32* xF; u32* xA; u32* xB; u32* ys;
    u16* pw1; u16* pw2;
    int nb;   // grid size used for scan chunking
};

// ---------------- phase device functions ----------------

// P0: zero deg + feats->bf16 cvt + weight packing (all independent)
__device__ void ph_init(const GArgs& a, int gtid, int gsz) {
    for (int i = gtid; i < NN; i += gsz) a.deg[i] = 0;
    for (int i = gtid; i < NN * (IND / 2); i += gsz) {
        float2 v = ((const float2*)a.feats)[i];
        a.xF[i] = (u32)f2bf(v.x) | ((u32)f2bf(v.y) << 16);
    }
    if (gtid < 4096) {                       // W1 [128x256] -> [ct16][ks4][lane64][j8]
        int idx = gtid;
        int lane = idx & 63, fid = idx >> 6;
        int ks = fid & 3, ct = fid >> 2;
        int quad = lane >> 4, m = lane & 15;
        int n = ct * 16 + m;
        u16* o = a.pw1 + (size_t)idx * 8;
        #pragma unroll
        for (int j = 0; j < 8; j++) {
            int k = ks * 32 + quad * 8 + j;
            o[j] = f2bf(a.W1[k * HD + n]);
        }
    } else if (gtid < 4096 + 1536) {         // W2 [256x40] -> [ct3][ks8][lane64][j8], pad to 48
        int idx = gtid - 4096;
        int lane = idx & 63, fid = idx >> 6;
        int ks = fid & 7, ct = fid >> 3;
        int quad = lane >> 4, m = lane & 15;
        int n = ct * 16 + m;
        u16* o = a.pw2 + (size_t)idx * 8;
        #pragma unroll
        for (int j = 0; j < 8; j++) {
            int k = ks * 32 + quad * 8 + j;
            o[j] = (n < NC) ? f2bf(a.W2[k * NC + n]) : (u16)0;
        }
    }
}

__device__ void ph_count(const GArgs& a, int gtid, int gsz) {
    for (int e = gtid; e < NE; e += gsz) atomicAdd(&a.deg[a.dst[e]], 1);
}

// P2: per-block chunk sums
__device__ void ph_scanA(const GArgs& a, int bid, int t) {
    __shared__ int sl[256];
    const int CH = (NN + a.nb - 1) / a.nb;
    const int sub = (CH + 255) / 256;
    const int b0 = bid * CH;
    const int lim = min(b0 + CH, NN);
    int s = 0;
    for (int j = 0; j < sub; j++) {
        int i = b0 + t * sub + j;
        if (i < lim) s += a.deg[i];
    }
    sl[t] = s;
    __syncthreads();
    for (int off = 128; off > 0; off >>= 1) {
        if (t < off) sl[t] += sl[t + off];
        __syncthreads();
    }
    if (t == 0) a.bsum[bid] = sl[0];
}

// P3: block 0 scans the nb block sums -> boff; writes rowptr[NN]
__device__ void ph_scanB(const GArgs& a, int bid, int t) {
    if (bid != 0) return;
    __shared__ int sl[256];
    const int nb = a.nb;
    const int sub = (nb + 255) / 256;
    int s = 0;
    for (int j = 0; j < sub; j++) {
        int i = t * sub + j;
        if (i < nb) s += a.bsum[i];
    }
    sl[t] = s;
    __syncthreads();
    for (int off = 1; off < 256; off <<= 1) {
        int v = (t >= off) ? sl[t - off] : 0;
        __syncthreads();
        sl[t] += v;
        __syncthreads();
    }
    int run = sl[t] - s;  // exclusive
    for (int j = 0; j < sub; j++) {
        int i = t * sub + j;
        if (i < nb) { a.boff[i] = run; run += a.bsum[i]; }
    }
    if (t == 255) a.rowptr[NN] = sl[255];
}

// P4: apply -> rowptr, cursor, norm
__device__ void ph_scanC(const GArgs& a, int bid, int t) {
    __shared__ int sl[256];
    const int CH = (NN + a.nb - 1) / a.nb;
    const int sub = (CH + 255) / 256;
    const int b0 = bid * CH;
    const int lim = min(b0 + CH, NN);
    int s = 0;
    for (int j = 0; j < sub; j++) {
        int i = b0 + t * sub + j;
        if (i < lim) s += a.deg[i];
    }
    sl[t] = s;
    __syncthreads();
    for (int off = 1; off < 256; off <<= 1) {
        int v = (t >= off) ? sl[t - off] : 0;
        __syncthreads();
        sl[t] += v;
        __syncthreads();
    }
    int run = a.boff[bid] + sl[t] - s;
    for (int j = 0; j < sub; j++) {
        int i = b0 + t * sub + j;
        if (i < lim) {
            int d = a.deg[i];
            a.rowptr[i] = run; a.cursor[i] = run; run += d;
            a.norm[i] = rsqrtf(fmaxf((float)d, 1.0f));
        }
    }
}

__device__ void ph_fill(const GArgs& a, int gtid, int gsz) {
    for (int e = gtid; e < NE; e += gsz) {
        int s = a.src[e], d = a.dst[e];
        int pos = atomicAdd(&a.cursor[d], 1);
        a.cv[pos] = make_int2(s, __float_as_int(a.norm[s] * a.norm[d]));
    }
}

// gather-SpMM over grid-stride rows; 8-edge ILP batches.
// LAST: ys = 0.25*(x0 + x1 + x + a) pre-scaled bf16 for the MLP.
template <int LAST>
__device__ void ph_spmm(const u32* __restrict__ x, u32* __restrict__ xnext,
                        const u32* __restrict__ x0, const u32* __restrict__ x1,
                        const int2* __restrict__ cv, const int* __restrict__ rowptr,
                        int gwid, int nw, int lane) {
    for (int row = gwid; row < NN; row += nw) {
        const int beg = rowptr[row], end = rowptr[row + 1];
        float a0 = 0.0f, a1 = 0.0f;
        if (beg < end) {
            for (int e = beg; e < end; e += 8) {
                int2 c8[8]; u32 u8[8];
                #pragma unroll
                for (int j = 0; j < 8; j++) {
                    const int ee = e + j;
                    c8[j] = cv[ee < end ? ee : end - 1];
                    if (ee >= end) c8[j].y = 0;
                }
                #pragma unroll
                for (int j = 0; j < 8; j++)
                    u8[j] = x[(size_t)c8[j].x * (IND / 2) + lane];
                #pragma unroll
                for (int j = 0; j < 8; j++) {
                    const float w = __int_as_float(c8[j].y);
                    a0 = fmaf(bf2f((u16)(u8[j] & 0xFFFFu)), w, a0);
                    a1 = fmaf(bf2f((u16)(u8[j] >> 16)),     w, a1);
                }
            }
        }
        const size_t ri = (size_t)row * (IND / 2) + lane;
        if (!LAST) {
            xnext[ri] = (u32)f2bf(a0) | ((u32)f2bf(a1) << 16);
        } else {
            const u32 v0 = x0[ri], v1 = x1[ri], v2 = x[ri];
            const float s0 = bf2f((u16)(v0 & 0xFFFFu)) + bf2f((u16)(v1 & 0xFFFFu))
                           + bf2f((u16)(v2 & 0xFFFFu)) + a0;
            const float s1 = bf2f((u16)(v0 >> 16)) + bf2f((u16)(v1 >> 16))
                           + bf2f((u16)(v2 >> 16)) + a1;
            xnext[ri] = (u32)f2bf(s0 * 0.25f) | ((u32)f2bf(s1 * 0.25f) << 16);
        }
    }
}

// ---------------- cooperative mega-kernel ----------------
__global__ __launch_bounds__(256) void coop_k(GArgs a) {
    cg::grid_group g = cg::this_grid();
    const int bid = blockIdx.x, t = threadIdx.x;
    const int gtid = bid * 256 + t, gsz = gridDim.x * 256;
    const int gwid = gtid >> 6, nw = gsz >> 6, lane = t & 63;

    ph_init(a, gtid, gsz);   g.sync();
    ph_count(a, gtid, gsz);  g.sync();
    ph_scanA(a, bid, t);     g.sync();
    ph_scanB(a, bid, t);     g.sync();
    ph_scanC(a, bid, t);     g.sync();
    ph_fill(a, gtid, gsz);   g.sync();
    ph_spmm<0>(a.xF, a.xA, nullptr, nullptr, a.cv, a.rowptr, gwid, nw, lane); g.sync();
    ph_spmm<0>(a.xA, a.xB, nullptr, nullptr, a.cv, a.rowptr, gwid, nw, lane); g.sync();
    ph_spmm<1>(a.xB, a.ys, a.xF, a.xA, a.cv, a.rowptr, gwid, nw, lane);
}

// ---------------- fallback wrappers (used only if cooperative launch fails) ----------------
__global__ __launch_bounds__(256) void f_init_k(GArgs a)  { ph_init(a, blockIdx.x * 256 + threadIdx.x, gridDim.x * 256); }
__global__ __launch_bounds__(256) void f_count_k(GArgs a) { ph_count(a, blockIdx.x * 256 + threadIdx.x, gridDim.x * 256); }
__global__ __launch_bounds__(256) void f_scanA_k(GArgs a) { ph_scanA(a, blockIdx.x, threadIdx.x); }
__global__ __launch_bounds__(256) void f_scanB_k(GArgs a) { ph_scanB(a, blockIdx.x, threadIdx.x); }
__global__ __launch_bounds__(256) void f_scanC_k(GArgs a) { ph_scanC(a, blockIdx.x, threadIdx.x); }
__global__ __launch_bounds__(256) void f_fill_k(GArgs a)  { ph_fill(a, blockIdx.x * 256 + threadIdx.x, gridDim.x * 256); }
template <int LAST>
__global__ __launch_bounds__(256) void f_spmm_k(GArgs a, const u32* x, u32* xnext,
                                                const u32* x0, const u32* x1) {
    const int gtid = blockIdx.x * 256 + threadIdx.x;
    ph_spmm<LAST>(x, xnext, x0, x1, a.cv, a.rowptr, gtid >> 6, (gridDim.x * 256) >> 6,
                  threadIdx.x & 63);
}

// ---------------- MFMA MLP (unchanged from round 8) ----------------
__global__ __launch_bounds__(256) void mlp_mfma_k(
    const u16* __restrict__ ys, const u16* __restrict__ pw1,
    const float* __restrict__ B1, const u16* __restrict__ pw2,
    const float* __restrict__ B2, float* __restrict__ out, int N)
{
    __shared__ u16 h_s[MT * HPAD];
    __shared__ float l_s[MT * LPAD];
    const int t = threadIdx.x;
    const int w = t >> 6, lane = t & 63;
    const int quad = lane >> 4, m = lane & 15;
    const int node0 = blockIdx.x * MT;

    int nodeA = node0 + w * 16 + m;
    if (nodeA > N - 1) nodeA = N - 1;
    bf16x8 av[4];
    #pragma unroll
    for (int ks = 0; ks < 4; ks++)
        av[ks] = *(const bf16x8*)(ys + (size_t)nodeA * IND + ks * 32 + quad * 8);

    #pragma unroll 4
    for (int ct = 0; ct < 16; ct++) {
        f32x4 acc = { 0.f, 0.f, 0.f, 0.f };
        #pragma unroll
        for (int ks = 0; ks < 4; ks++) {
            const bf16x8 b = *(const bf16x8*)(pw1 + (size_t)((ct * 4 + ks) * 64 + lane) * 8);
            acc = __builtin_amdgcn_mfma_f32_16x16x32_bf16(av[ks], b, acc, 0, 0, 0);
        }
        const float b1c = B1[ct * 16 + m];
        #pragma unroll
        for (int r = 0; r < 4; r++) {
            const float hv = fmaxf(acc[r] + b1c, 0.0f);
            h_s[(w * 16 + quad * 4 + r) * HPAD + ct * 16 + m] = f2bf(hv);
        }
    }

    f32x4 acc2[3];
    #pragma unroll
    for (int ct = 0; ct < 3; ct++) acc2[ct] = (f32x4){ 0.f, 0.f, 0.f, 0.f };
    #pragma unroll
    for (int ks = 0; ks < 8; ks++) {
        const bf16x8 a = *(const bf16x8*)&h_s[(w * 16 + m) * HPAD + ks * 32 + quad * 8];
        #pragma unroll
        for (int ct = 0; ct < 3; ct++) {
            const bf16x8 b = *(const bf16x8*)(pw2 + (size_t)((ct * 8 + ks) * 64 + lane) * 8);
            acc2[ct] = __builtin_amdgcn_mfma_f32_16x16x32_bf16(a, b, acc2[ct], 0, 0, 0);
        }
    }
    #pragma unroll
    for (int ct = 0; ct < 3; ct++) {
        const int cg2 = ct * 16 + m;
        const float b2c = (cg2 < NC) ? B2[cg2] : 0.0f;
        #pragma unroll
        for (int r = 0; r < 4; r++)
            l_s[(w * 16 + quad * 4 + r) * LPAD + cg2] = acc2[ct][r] + b2c;
    }
    __syncthreads();

    if (t < MT) {
        const int node = node0 + t;
        if (node < N) {
            const float* ln = &l_s[t * LPAD];
            float mx = -1e30f;
            #pragma unroll
            for (int c = 0; c < NC; c++) mx = fmaxf(mx, ln[c]);
            float s = 0.0f;
            #pragma unroll
            for (int c = 0; c < NC; c++) s += __expf(ln[c] - mx);
            const float lse = mx + __logf(s);
            float4* o = (float4*)(out + (size_t)node * NC);
            #pragma unroll
            for (int c4 = 0; c4 < NC / 4; c4++) {
                float4 v;
                v.x = ln[c4 * 4 + 0] - lse;
                v.y = ln[c4 * 4 + 1] - lse;
                v.z = ln[c4 * 4 + 2] - lse;
                v.w = ln[c4 * 4 + 3] - lse;
                o[c4] = v;
            }
        }
    }
}

extern "C" void kernel_launch(void* const* d_in, const int* in_sizes, int n_in,
                              void* d_out, int out_size, void* d_ws, size_t ws_size,
                              hipStream_t stream) {
    const float* feats = (const float*)d_in[0];
    const int* src = (const int*)d_in[1];
    const int* dst = (const int*)d_in[2];
    const float* W1 = (const float*)d_in[3];
    const float* B1 = (const float*)d_in[4];
    const float* W2 = (const float*)d_in[5];
    const float* B2 = (const float*)d_in[6];
    float* out = (float*)d_out;

    char* base = (char*)d_ws;
    size_t off = 0;
    auto alloc = [&](size_t bytes) -> void* {
        void* p = base + off;
        off += (bytes + 255) & ~(size_t)255;
        return p;
    };
    GArgs a;
    a.src = src; a.dst = dst; a.feats = feats; a.W1 = W1; a.W2 = W2;
    a.deg    = (int*)  alloc((size_t)NN * 4);
    a.rowptr = (int*)  alloc((size_t)(NN + 1) * 4);
    a.cursor = (int*)  alloc((size_t)NN * 4);
    a.norm   = (float*)alloc((size_t)NN * 4);
    a.bsum   = (int*)  alloc((size_t)4096 * 4);
    a.boff   = (int*)  alloc((size_t)4096 * 4);
    a.cv     = (int2*) alloc((size_t)NE * 8);
    a.pw1    = (u16*)  alloc((size_t)16 * 4 * 64 * 8 * 2);
    a.pw2    = (u16*)  alloc((size_t)3 * 8 * 64 * 8 * 2);
    a.xF     = (u32*)  alloc((size_t)NN * (IND / 2) * 4);
    a.xA     = (u32*)  alloc((size_t)NN * (IND / 2) * 4);
    a.xB     = (u32*)  alloc((size_t)NN * (IND / 2) * 4);
    a.ys     = (u32*)  alloc((size_t)NN * (IND / 2) * 4);

    // co-residency-bounded grid for the cooperative kernel
    int nbpc = 0;
    if (hipOccupancyMaxActiveBlocksPerMultiprocessor(&nbpc, (const void*)coop_k, 256, 0)
            != hipSuccess || nbpc <= 0)
        nbpc = 2;
    int nb = nbpc * 256;            // 256 CUs on MI355X
    if (nb > 4096) nb = 4096;
    if (nb < 512)  nb = 512;
    a.nb = nb;

    void* params[] = { &a };
    hipError_t err = hipLaunchCooperativeKernel((const void*)coop_k, dim3(nb), dim3(256),
                                                params, 0, stream);
    if (err != hipSuccess) {
        // fallback: identical phases as classic kernels
        f_init_k <<<1024, 256, 0, stream>>>(a);
        f_count_k<<<(NE + 255) / 256, 256, 0, stream>>>(a);
        f_scanA_k<<<nb, 256, 0, stream>>>(a);
        f_scanB_k<<<1, 256, 0, stream>>>(a);
        f_scanC_k<<<nb, 256, 0, stream>>>(a);
        f_fill_k <<<(NE + 255) / 256, 256, 0, stream>>>(a);
        const int sgrid = (NN * 64 + 255) / 256;
        f_spmm_k<0><<<sgrid, 256, 0, stream>>>(a, a.xF, a.xA, nullptr, nullptr);
        f_spmm_k<0><<<sgrid, 256, 0, stream>>>(a, a.xA, a.xB, nullptr, nullptr);
        f_spmm_k<1><<<sgrid, 256, 0, stream>>>(a, a.xB, a.ys, a.xF, a.xA);
    }

    const int mgrid = (NN + MT - 1) / MT;
    mlp_mfma_k<<<mgrid, 256, 0, stream>>>((const u16*)a.ys, a.pw1, B1, a.pw2, B2, out, NN);
}

// Round 10
// 365.839 us; speedup vs baseline: 3.4943x; 3.4943x over previous
//
#include <hip/hip_runtime.h>

#define NN 100000
#define NE 640000
#define IND 128
#define HD 256
#define NC 40
#define MT 64      // nodes per block in MLP
#define HPAD 264   // h_s row stride (bf16 elems)
#define LPAD 52    // l_s row stride (f32)
#define YPAD 68    // ys_s row stride (u32): 272B, 16B-aligned, 2-way-bank only

typedef unsigned short u16;
typedef unsigned int u32;
typedef __attribute__((ext_vector_type(8))) short bf16x8;
typedef __attribute__((ext_vector_type(4))) float f32x4;

__device__ __forceinline__ float bf2f(u16 u) {
    union { u32 i; float f; } c; c.i = ((u32)u) << 16; return c.f;
}
__device__ __forceinline__ u16 f2bf(float f) {
    union { float f; u32 i; } c; c.f = f;
    u32 i = c.i;
    return (u16)((i + 0x7FFFu + ((i >> 16) & 1u)) >> 16); // RNE
}

// P1: deg count + feats->bf16 + W1/W2 fragment packing (deg pre-zeroed by memset)
__global__ __launch_bounds__(256) void prep_k(
    const int* __restrict__ dst, int* __restrict__ deg,
    const float2* __restrict__ feats, u32* __restrict__ xF,
    const float* __restrict__ W1, const float* __restrict__ W2,
    u16* __restrict__ pw1, u16* __restrict__ pw2)
{
    const int gtid = blockIdx.x * 256 + threadIdx.x, gsz = gridDim.x * 256;
    if (gtid < 4096) {                       // W1 [128x256] -> [ct16][ks4][lane64][j8]
        int lane = gtid & 63, fid = gtid >> 6;
        int ks = fid & 3, ct = fid >> 2;
        int quad = lane >> 4, m = lane & 15;
        int n = ct * 16 + m;
        u16* o = pw1 + (size_t)gtid * 8;
        #pragma unroll
        for (int j = 0; j < 8; j++) o[j] = f2bf(W1[(ks * 32 + quad * 8 + j) * HD + n]);
    } else if (gtid < 4096 + 1536) {         // W2 [256x40] -> [ct3][ks8][lane64][j8] pad 48
        int idx = gtid - 4096;
        int lane = idx & 63, fid = idx >> 6;
        int ks = fid & 7, ct = fid >> 3;
        int quad = lane >> 4, m = lane & 15;
        int n = ct * 16 + m;
        u16* o = pw2 + (size_t)idx * 8;
        #pragma unroll
        for (int j = 0; j < 8; j++)
            o[j] = (n < NC) ? f2bf(W2[(ks * 32 + quad * 8 + j) * NC + n]) : (u16)0;
    }
    for (int i = gtid; i < NN * (IND / 2); i += gsz) {
        float2 v = feats[i];
        xF[i] = (u32)f2bf(v.x) | ((u32)f2bf(v.y) << 16);
    }
    for (int e = gtid; e < NE; e += gsz) atomicAdd(&deg[dst[e]], 1);
}

// P2: CSR segment allocation WITHOUT a prefix scan: wave-scan + one atomicAdd per wave.
// Segments are disjoint (order irrelevant). rb[i] = {beg, end}; cursor; norm.
__global__ __launch_bounds__(256) void alloc_k(
    const int* __restrict__ deg, int* __restrict__ gtotal,
    int2* __restrict__ rb, int* __restrict__ cursor, float* __restrict__ norm)
{
    const int gtid = blockIdx.x * 256 + threadIdx.x;
    const int lane = threadIdx.x & 63;
    const int i0 = gtid * 4;
    int d[4]; int own = 0;
    #pragma unroll
    for (int j = 0; j < 4; j++) {
        d[j] = (i0 + j < NN) ? deg[i0 + j] : 0;
        own += d[j];
    }
    int incl = own;
    #pragma unroll
    for (int off = 1; off < 64; off <<= 1) {
        int v = __shfl_up(incl, off);
        if (lane >= off) incl += v;
    }
    int base = 0;
    if (lane == 63) base = atomicAdd(gtotal, incl);
    base = __shfl(base, 63);
    int run = base + incl - own;
    #pragma unroll
    for (int j = 0; j < 4; j++) {
        int i = i0 + j;
        if (i < NN) {
            cursor[i] = run;
            rb[i] = make_int2(run, run + d[j]);
            norm[i] = rsqrtf(fmaxf((float)d[j], 1.0f));
            run += d[j];
        }
    }
}

// P3: CSR fill: cv = {src, bits(norm[src]*norm[dst])}
__global__ void fill_k(const int* __restrict__ src, const int* __restrict__ dst,
                       const float* __restrict__ norm, int* __restrict__ cursor,
                       int2* __restrict__ cv, int E) {
    int e = blockIdx.x * 256 + threadIdx.x;
    if (e >= E) return;
    int s = src[e], d = dst[e];
    int pos = atomicAdd(&cursor[d], 1);
    cv[pos] = make_int2(s, __float_as_int(norm[s] * norm[d]));
}

// 8-edge ILP gather for one row; returns packed accumulation into a0/a1
__device__ __forceinline__ void row_gather(const u32* __restrict__ x,
                                           const int2* __restrict__ cv,
                                           int beg, int end, int lane,
                                           float& a0, float& a1) {
    for (int e = beg; e < end; e += 8) {
        int2 c8[8]; u32 u8[8];
        #pragma unroll
        for (int j = 0; j < 8; j++) {
            const int ee = e + j;
            c8[j] = cv[ee < end ? ee : end - 1];
            if (ee >= end) c8[j].y = 0;
        }
        #pragma unroll
        for (int j = 0; j < 8; j++)
            u8[j] = x[(size_t)c8[j].x * (IND / 2) + lane];
        #pragma unroll
        for (int j = 0; j < 8; j++) {
            const float w = __int_as_float(c8[j].y);
            a0 = fmaf(bf2f((u16)(u8[j] & 0xFFFFu)), w, a0);
            a1 = fmaf(bf2f((u16)(u8[j] >> 16)),     w, a1);
        }
    }
}

// P4/P5: standalone gather-SpMM, one wave per dst row
__global__ __launch_bounds__(256) void spmm_k(
    const u32* __restrict__ x, u32* __restrict__ xnext,
    const int2* __restrict__ rb, const int2* __restrict__ cv, int N)
{
    const int wid = (blockIdx.x * 256 + threadIdx.x) >> 6;
    const int lane = threadIdx.x & 63;
    if (wid >= N) return;
    const int2 be = rb[wid];
    float a0 = 0.0f, a1 = 0.0f;
    row_gather(x, cv, be.x, be.y, lane, a0, a1);
    xnext[(size_t)wid * (IND / 2) + lane] = (u32)f2bf(a0) | ((u32)f2bf(a1) << 16);
}

// P6: fused final SpMM + sum + MLP + log_softmax.
// Wave w computes ys rows w*16..w*16+15 into LDS (the exact rows it reads as A),
// so no barrier between spmm part and A-fragment load (same-wave DS ordering).
__global__ __launch_bounds__(256) void spmm_mlp_k(
    const u32* __restrict__ xB, const u32* __restrict__ xF, const u32* __restrict__ xA,
    const int2* __restrict__ rb, const int2* __restrict__ cv,
    const u16* __restrict__ pw1, const float* __restrict__ B1,
    const u16* __restrict__ pw2, const float* __restrict__ B2,
    float* __restrict__ out, int N)
{
    __shared__ u32 ys_s[MT * YPAD];      // 17.4 KB (overlaid by l_s later)
    __shared__ u16 h_s[MT * HPAD];       // 33.8 KB
    float* l_s = (float*)ys_s;           // overlay after barrier
    const int t = threadIdx.x;
    const int w = t >> 6, lane = t & 63;
    const int quad = lane >> 4, m = lane & 15;
    const int node0 = blockIdx.x * MT;

    // ---- spmm step 3 + final sum, rows w*16 .. w*16+15 ----
    for (int r = w * 16; r < w * 16 + 16; r++) {
        const int node = node0 + r;
        if (node < N) {
            const int2 be = rb[node];
            float a0 = 0.0f, a1 = 0.0f;
            row_gather(xB, cv, be.x, be.y, lane, a0, a1);
            const size_t ri = (size_t)node * (IND / 2) + lane;
            const u32 v0 = xF[ri], v1 = xA[ri], v2 = xB[ri];
            const float s0 = bf2f((u16)(v0 & 0xFFFFu)) + bf2f((u16)(v1 & 0xFFFFu))
                           + bf2f((u16)(v2 & 0xFFFFu)) + a0;
            const float s1 = bf2f((u16)(v0 >> 16)) + bf2f((u16)(v1 >> 16))
                           + bf2f((u16)(v2 >> 16)) + a1;
            ys_s[r * YPAD + lane] = (u32)f2bf(s0 * 0.25f) | ((u32)f2bf(s1 * 0.25f) << 16);
        } else {
            ys_s[r * YPAD + lane] = 0;
        }
    }

    // ---- A fragments from own rows (same-wave LDS, ordered) ----
    bf16x8 av[4];
    #pragma unroll
    for (int ks = 0; ks < 4; ks++)
        av[ks] = *(const bf16x8*)&ys_s[(w * 16 + m) * YPAD + ks * 16 + quad * 4];
    __syncthreads();   // everyone's av loaded before l_s overlays ys_s

    // ---- layer 1 ----
    #pragma unroll 4
    for (int ct = 0; ct < 16; ct++) {
        f32x4 acc = { 0.f, 0.f, 0.f, 0.f };
        #pragma unroll
        for (int ks = 0; ks < 4; ks++) {
            const bf16x8 b = *(const bf16x8*)(pw1 + (size_t)((ct * 4 + ks) * 64 + lane) * 8);
            acc = __builtin_amdgcn_mfma_f32_16x16x32_bf16(av[ks], b, acc, 0, 0, 0);
        }
        const float b1c = B1[ct * 16 + m];
        #pragma unroll
        for (int r = 0; r < 4; r++) {
            const float hv = fmaxf(acc[r] + b1c, 0.0f);
            h_s[(w * 16 + quad * 4 + r) * HPAD + ct * 16 + m] = f2bf(hv);
        }
    }

    // ---- layer 2 ----
    f32x4 acc2[3];
    #pragma unroll
    for (int ct = 0; ct < 3; ct++) acc2[ct] = (f32x4){ 0.f, 0.f, 0.f, 0.f };
    #pragma unroll
    for (int ks = 0; ks < 8; ks++) {
        const bf16x8 a = *(const bf16x8*)&h_s[(w * 16 + m) * HPAD + ks * 32 + quad * 8];
        #pragma unroll
        for (int ct = 0; ct < 3; ct++) {
            const bf16x8 b = *(const bf16x8*)(pw2 + (size_t)((ct * 8 + ks) * 64 + lane) * 8);
            acc2[ct] = __builtin_amdgcn_mfma_f32_16x16x32_bf16(a, b, acc2[ct], 0, 0, 0);
        }
    }
    #pragma unroll
    for (int ct = 0; ct < 3; ct++) {
        const int cg = ct * 16 + m;
        const float b2c = (cg < NC) ? B2[cg] : 0.0f;
        #pragma unroll
        for (int r = 0; r < 4; r++)
            l_s[(w * 16 + quad * 4 + r) * LPAD + cg] = acc2[ct][r] + b2c;
    }
    __syncthreads();

    // ---- log_softmax epilogue ----
    if (t < MT) {
        const int node = node0 + t;
        if (node < N) {
            const float* ln = &l_s[t * LPAD];
            float mx = -1e30f;
            #pragma unroll
            for (int c = 0; c < NC; c++) mx = fmaxf(mx, ln[c]);
            float s = 0.0f;
            #pragma unroll
            for (int c = 0; c < NC; c++) s += __expf(ln[c] - mx);
            const float lse = mx + __logf(s);
            float4* o = (float4*)(out + (size_t)node * NC);
            #pragma unroll
            for (int c4 = 0; c4 < NC / 4; c4++) {
                float4 v;
                v.x = ln[c4 * 4 + 0] - lse;
                v.y = ln[c4 * 4 + 1] - lse;
                v.z = ln[c4 * 4 + 2] - lse;
                v.w = ln[c4 * 4 + 3] - lse;
                o[c4] = v;
            }
        }
    }
}

extern "C" void kernel_launch(void* const* d_in, const int* in_sizes, int n_in,
                              void* d_out, int out_size, void* d_ws, size_t ws_size,
                              hipStream_t stream) {
    const float* feats = (const float*)d_in[0];
    const int* src = (const int*)d_in[1];
    const int* dst = (const int*)d_in[2];
    const float* W1 = (const float*)d_in[3];
    const float* B1 = (const float*)d_in[4];
    const float* W2 = (const float*)d_in[5];
    const float* B2 = (const float*)d_in[6];
    float* out = (float*)d_out;

    char* base = (char*)d_ws;
    size_t off = 0;
    auto alloc = [&](size_t bytes) -> void* {
        void* p = base + off;
        off += (bytes + 255) & ~(size_t)255;
        return p;
    };
    int*   deg    = (int*)  alloc((size_t)NN * 4);
    int*   gtotal = (int*)  alloc(256);          // contiguous after deg; zeroed together
    float* norm   = (float*)alloc((size_t)NN * 4);
    int*   cursor = (int*)  alloc((size_t)NN * 4);
    int2*  rb     = (int2*) alloc((size_t)NN * 8);
    int2*  cv     = (int2*) alloc((size_t)NE * 8);
    u16*   pw1    = (u16*)  alloc((size_t)16 * 4 * 64 * 8 * 2);
    u16*   pw2    = (u16*)  alloc((size_t)3 * 8 * 64 * 8 * 2);
    u32*   xF     = (u32*)  alloc((size_t)NN * (IND / 2) * 4);
    u32*   xA     = (u32*)  alloc((size_t)NN * (IND / 2) * 4);
    u32*   xB     = (u32*)  alloc((size_t)NN * (IND / 2) * 4);

    // zero deg + gtotal (contiguous allocations)
    hipMemsetAsync(deg, 0, ((size_t)NN * 4 + 255 & ~(size_t)255) + 256, stream);

    prep_k<<<2048, 256, 0, stream>>>(dst, deg, (const float2*)feats, xF, W1, W2, pw1, pw2);
    alloc_k<<<(NN + 1023) / 1024, 256, 0, stream>>>(deg, gtotal, rb, cursor, norm);
    fill_k<<<(NE + 255) / 256, 256, 0, stream>>>(src, dst, norm, cursor, cv, NE);

    const int sgrid = (NN * 64 + 255) / 256;
    spmm_k<<<sgrid, 256, 0, stream>>>(xF, xA, rb, cv, NN);
    spmm_k<<<sgrid, 256, 0, stream>>>(xA, xB, rb, cv, NN);

    const int mgrid = (NN + MT - 1) / MT;
    spmm_mlp_k<<<mgrid, 256, 0, stream>>>(xB, xF, xA, rb, cv, pw1, B1, pw2, B2, out, NN);
}

// Round 11
// 317.211 us; speedup vs baseline: 4.0299x; 1.1533x over previous
//
#include <hip/hip_runtime.h>

#define NN 100000
#define NE 640000
#define IND 128
#define HD 256
#define NC 40
#define MT 64      // nodes per block in MLP
#define HPAD 264   // h_s row stride (bf16 elems)
#define LPAD 52    // l_s row stride (f32)

typedef unsigned short u16;
typedef unsigned int u32;
typedef __attribute__((ext_vector_type(8))) short bf16x8;
typedef __attribute__((ext_vector_type(4))) float f32x4;

__device__ __forceinline__ float bf2f(u16 u) {
    union { u32 i; float f; } c; c.i = ((u32)u) << 16; return c.f;
}
__device__ __forceinline__ u16 f2bf(float f) {
    union { float f; u32 i; } c; c.f = f;
    u32 i = c.i;
    return (u16)((i + 0x7FFFu + ((i >> 16) & 1u)) >> 16); // RNE
}

// P1: deg count + feats->bf16 + W1/W2 fragment packing (deg pre-zeroed by memset)
__global__ __launch_bounds__(256) void prep_k(
    const int* __restrict__ dst, int* __restrict__ deg,
    const float2* __restrict__ feats, u32* __restrict__ xF,
    const float* __restrict__ W1, const float* __restrict__ W2,
    u16* __restrict__ pw1, u16* __restrict__ pw2)
{
    const int gtid = blockIdx.x * 256 + threadIdx.x, gsz = gridDim.x * 256;
    if (gtid < 4096) {                       // W1 [128x256] -> [ct16][ks4][lane64][j8]
        int lane = gtid & 63, fid = gtid >> 6;
        int ks = fid & 3, ct = fid >> 2;
        int quad = lane >> 4, m = lane & 15;
        int n = ct * 16 + m;
        u16* o = pw1 + (size_t)gtid * 8;
        #pragma unroll
        for (int j = 0; j < 8; j++) o[j] = f2bf(W1[(ks * 32 + quad * 8 + j) * HD + n]);
    } else if (gtid < 4096 + 1536) {         // W2 [256x40] -> [ct3][ks8][lane64][j8] pad 48
        int idx = gtid - 4096;
        int lane = idx & 63, fid = idx >> 6;
        int ks = fid & 7, ct = fid >> 3;
        int quad = lane >> 4, m = lane & 15;
        int n = ct * 16 + m;
        u16* o = pw2 + (size_t)idx * 8;
        #pragma unroll
        for (int j = 0; j < 8; j++)
            o[j] = (n < NC) ? f2bf(W2[(ks * 32 + quad * 8 + j) * NC + n]) : (u16)0;
    }
    for (int i = gtid; i < NN * (IND / 2); i += gsz) {
        float2 v = feats[i];
        xF[i] = (u32)f2bf(v.x) | ((u32)f2bf(v.y) << 16);
    }
    for (int e = gtid; e < NE; e += gsz) atomicAdd(&deg[dst[e]], 1);
}

// P2: CSR segment allocation without a global scan: wave-scan + one atomicAdd/wave.
__global__ __launch_bounds__(256) void alloc_k(
    const int* __restrict__ deg, int* __restrict__ gtotal,
    int2* __restrict__ rb, int* __restrict__ cursor, float* __restrict__ norm)
{
    const int gtid = blockIdx.x * 256 + threadIdx.x;
    const int lane = threadIdx.x & 63;
    const int i0 = gtid * 4;
    int d[4]; int own = 0;
    #pragma unroll
    for (int j = 0; j < 4; j++) {
        d[j] = (i0 + j < NN) ? deg[i0 + j] : 0;
        own += d[j];
    }
    int incl = own;
    #pragma unroll
    for (int off = 1; off < 64; off <<= 1) {
        int v = __shfl_up(incl, off);
        if (lane >= off) incl += v;
    }
    int base = 0;
    if (lane == 63) base = atomicAdd(gtotal, incl);
    base = __shfl(base, 63);
    int run = base + incl - own;
    #pragma unroll
    for (int j = 0; j < 4; j++) {
        int i = i0 + j;
        if (i < NN) {
            cursor[i] = run;
            rb[i] = make_int2(run, run + d[j]);
            norm[i] = rsqrtf(fmaxf((float)d[j], 1.0f));
            run += d[j];
        }
    }
}

// P3: CSR fill: cv = {src, bits(norm[src]*norm[dst])}
__global__ void fill_k(const int* __restrict__ src, const int* __restrict__ dst,
                       const float* __restrict__ norm, int* __restrict__ cursor,
                       int2* __restrict__ cv, int E) {
    int e = blockIdx.x * 256 + threadIdx.x;
    if (e >= E) return;
    int s = src[e], d = dst[e];
    int pos = atomicAdd(&cursor[d], 1);
    cv[pos] = make_int2(s, __float_as_int(norm[s] * norm[d]));
}

// Paired-row gather: 32 lanes per row, 8 B/lane (4 bf16), 8-edge ILP per half.
// Every load instruction serves 2 edges (one per half).
__device__ __forceinline__ void row_gather2(const u32* __restrict__ x,
                                            const int2* __restrict__ cv,
                                            int beg, int end, int nbt, int hl,
                                            float a[4]) {
    for (int b = 0; b < nbt; b++) {
        const int e0 = beg + b * 8;
        int2 c8[8]; uint2 u8[8];
        #pragma unroll
        for (int j = 0; j < 8; j++) {
            const int ee = e0 + j;
            c8[j] = cv[min(ee, NE - 1)];
            if (ee >= end) c8[j].y = 0;   // w = 0
        }
        #pragma unroll
        for (int j = 0; j < 8; j++)
            u8[j] = ((const uint2*)x)[(size_t)c8[j].x * 32 + hl];
        #pragma unroll
        for (int j = 0; j < 8; j++) {
            const float w = __int_as_float(c8[j].y);
            a[0] = fmaf(bf2f((u16)(u8[j].x & 0xFFFFu)), w, a[0]);
            a[1] = fmaf(bf2f((u16)(u8[j].x >> 16)),     w, a[1]);
            a[2] = fmaf(bf2f((u16)(u8[j].y & 0xFFFFu)), w, a[2]);
            a[3] = fmaf(bf2f((u16)(u8[j].y >> 16)),     w, a[3]);
        }
    }
}

// P4/P5: gather-SpMM, 2 rows per wave (rows 2*wid, 2*wid+1).
// LAST: ys = 0.25*(x0 + x1 + x + a), pre-scaled bf16 for the MLP.
template <int LAST>
__global__ __launch_bounds__(256) void spmm_k(
    const u32* __restrict__ x, u32* __restrict__ xnext,
    const u32* __restrict__ x0, const u32* __restrict__ x1, 
    const int2* __restrict__ rb, const int2* __restrict__ cv)
{
    const int wid = (blockIdx.x * 256 + threadIdx.x) >> 6;
    const int lane = threadIdx.x & 63;
    const int half = lane >> 5, hl = lane & 31;
    const int row = wid * 2 + half;
    if (row >= NN) return;
    const int2 be = rb[row];
    const int nb = (be.y - be.x + 7) >> 3;
    const int onb = __shfl_xor(nb, 32);
    const int nbt = max(nb, onb);
    float a[4] = { 0.f, 0.f, 0.f, 0.f };
    row_gather2(x, cv, be.x, be.y, nbt, hl, a);

    const size_t ri = (size_t)row * 32 + hl;
    uint2 o;
    if (!LAST) {
        o.x = (u32)f2bf(a[0]) | ((u32)f2bf(a[1]) << 16);
        o.y = (u32)f2bf(a[2]) | ((u32)f2bf(a[3]) << 16);
    } else {
        const uint2 v0 = ((const uint2*)x0)[ri];
        const uint2 v1 = ((const uint2*)x1)[ri];
        const uint2 v2 = ((const uint2*)x)[ri];
        const float s0 = bf2f((u16)(v0.x & 0xFFFFu)) + bf2f((u16)(v1.x & 0xFFFFu))
                       + bf2f((u16)(v2.x & 0xFFFFu)) + a[0];
        const float s1 = bf2f((u16)(v0.x >> 16)) + bf2f((u16)(v1.x >> 16))
                       + bf2f((u16)(v2.x >> 16)) + a[1];
        const float s2 = bf2f((u16)(v0.y & 0xFFFFu)) + bf2f((u16)(v1.y & 0xFFFFu))
                       + bf2f((u16)(v2.y & 0xFFFFu)) + a[2];
        const float s3 = bf2f((u16)(v0.y >> 16)) + bf2f((u16)(v1.y >> 16))
                       + bf2f((u16)(v2.y >> 16)) + a[3];
        o.x = (u32)f2bf(s0 * 0.25f) | ((u32)f2bf(s1 * 0.25f) << 16);
        o.y = (u32)f2bf(s2 * 0.25f) | ((u32)f2bf(s3 * 0.25f) << 16);
    }
    ((uint2*)xnext)[ri] = o;
}

// P6: MFMA MLP (round-8 structure): 64 nodes/block, 4 waves x 16-node tiles.
__global__ __launch_bounds__(256) void mlp_mfma_k(
    const u16* __restrict__ ys, const u16* __restrict__ pw1,
    const float* __restrict__ B1, const u16* __restrict__ pw2,
    const float* __restrict__ B2, float* __restrict__ out, int N)
{
    __shared__ u16 h_s[MT * HPAD];
    __shared__ float l_s[MT * LPAD];
    const int t = threadIdx.x;
    const int w = t >> 6, lane = t & 63;
    const int quad = lane >> 4, m = lane & 15;
    const int node0 = blockIdx.x * MT;

    int nodeA = node0 + w * 16 + m;
    if (nodeA > N - 1) nodeA = N - 1;
    bf16x8 av[4];
    #pragma unroll
    for (int ks = 0; ks < 4; ks++)
        av[ks] = *(const bf16x8*)(ys + (size_t)nodeA * IND + ks * 32 + quad * 8);

    #pragma unroll 4
    for (int ct = 0; ct < 16; ct++) {
        f32x4 acc = { 0.f, 0.f, 0.f, 0.f };
        #pragma unroll
        for (int ks = 0; ks < 4; ks++) {
            const bf16x8 b = *(const bf16x8*)(pw1 + (size_t)((ct * 4 + ks) * 64 + lane) * 8);
            acc = __builtin_amdgcn_mfma_f32_16x16x32_bf16(av[ks], b, acc, 0, 0, 0);
        }
        const float b1c = B1[ct * 16 + m];
        #pragma unroll
        for (int r = 0; r < 4; r++) {
            const float hv = fmaxf(acc[r] + b1c, 0.0f);
            h_s[(w * 16 + quad * 4 + r) * HPAD + ct * 16 + m] = f2bf(hv);
        }
    }

    f32x4 acc2[3];
    #pragma unroll
    for (int ct = 0; ct < 3; ct++) acc2[ct] = (f32x4){ 0.f, 0.f, 0.f, 0.f };
    #pragma unroll
    for (int ks = 0; ks < 8; ks++) {
        const bf16x8 a = *(const bf16x8*)&h_s[(w * 16 + m) * HPAD + ks * 32 + quad * 8];
        #pragma unroll
        for (int ct = 0; ct < 3; ct++) {
            const bf16x8 b = *(const bf16x8*)(pw2 + (size_t)((ct * 8 + ks) * 64 + lane) * 8);
            acc2[ct] = __builtin_amdgcn_mfma_f32_16x16x32_bf16(a, b, acc2[ct], 0, 0, 0);
        }
    }
    #pragma unroll
    for (int ct = 0; ct < 3; ct++) {
        const int cg = ct * 16 + m;
        const float b2c = (cg < NC) ? B2[cg] : 0.0f;
        #pragma unroll
        for (int r = 0; r < 4; r++)
            l_s[(w * 16 + quad * 4 + r) * LPAD + cg] = acc2[ct][r] + b2c;
    }
    __syncthreads();

    if (t < MT) {
        const int node = node0 + t;
        if (node < N) {
            const float* ln = &l_s[t * LPAD];
            float mx = -1e30f;
            #pragma unroll
            for (int c = 0; c < NC; c++) mx = fmaxf(mx, ln[c]);
            float s = 0.0f;
            #pragma unroll
            for (int c = 0; c < NC; c++) s += __expf(ln[c] - mx);
            const float lse = mx + __logf(s);
            float4* o = (float4*)(out + (size_t)node * NC);
            #pragma unroll
            for (int c4 = 0; c4 < NC / 4; c4++) {
                float4 v;
                v.x = ln[c4 * 4 + 0] - lse;
                v.y = ln[c4 * 4 + 1] - lse;
                v.z = ln[c4 * 4 + 2] - lse;
                v.w = ln[c4 * 4 + 3] - lse;
                o[c4] = v;
            }
        }
    }
}

extern "C" void kernel_launch(void* const* d_in, const int* in_sizes, int n_in,
                              void* d_out, int out_size, void* d_ws, size_t ws_size,
                              hipStream_t stream) {
    const float* feats = (const float*)d_in[0];
    const int* src = (const int*)d_in[1];
    const int* dst = (const int*)d_in[2];
    const float* W1 = (const float*)d_in[3];
    const float* B1 = (const float*)d_in[4];
    const float* W2 = (const float*)d_in[5];
    const float* B2 = (const float*)d_in[6];
    float* out = (float*)d_out;

    char* base = (char*)d_ws;
    size_t off = 0;
    auto alloc = [&](size_t bytes) -> void* {
        void* p = base + off;
        off += (bytes + 255) & ~(size_t)255;
        return p;
    };
    int*   deg    = (int*)  alloc((size_t)NN * 4);
    int*   gtotal = (int*)  alloc(256);          // contiguous after deg; zeroed together
    float* norm   = (float*)alloc((size_t)NN * 4);
    int*   cursor = (int*)  alloc((size_t)NN * 4);
    int2*  rb     = (int2*) alloc((size_t)NN * 8);
    int2*  cv     = (int2*) alloc((size_t)NE * 8);
    u16*   pw1    = (u16*)  alloc((size_t)16 * 4 * 64 * 8 * 2);
    u16*   pw2    = (u16*)  alloc((size_t)3 * 8 * 64 * 8 * 2);
    u32*   xF     = (u32*)  alloc((size_t)NN * (IND / 2) * 4);
    u32*   xA     = (u32*)  alloc((size_t)NN * (IND / 2) * 4);
    u32*   xB     = (u32*)  alloc((size_t)NN * (IND / 2) * 4);
    u32*   ys     = (u32*)  alloc((size_t)NN * (IND / 2) * 4);

    hipMemsetAsync(deg, 0, (((size_t)NN * 4 + 255) & ~(size_t)255) + 256, stream);

    prep_k<<<2048, 256, 0, stream>>>(dst, deg, (const float2*)feats, xF, W1, W2, pw1, pw2);
    alloc_k<<<(NN + 1023) / 1024, 256, 0, stream>>>(deg, gtotal, rb, cursor, norm);
    fill_k<<<(NE + 255) / 256, 256, 0, stream>>>(src, dst, norm, cursor, cv, NE);

    const int npairs = (NN + 1) / 2;                 // waves (2 rows each)
    const int sgrid = (npairs * 64 + 255) / 256;
    spmm_k<0><<<sgrid, 256, 0, stream>>>(xF, xA, nullptr, nullptr, rb, cv);
    spmm_k<0><<<sgrid, 256, 0, stream>>>(xA, xB, nullptr, nullptr, rb, cv);
    spmm_k<1><<<sgrid, 256, 0, stream>>>(xB, ys, xF, xA, rb, cv);

    const int mgrid = (NN + MT - 1) / MT;
    mlp_mfma_k<<<mgrid, 256, 0, stream>>>((const u16*)ys, pw1, B1, pw2, B2, out, NN);
}